// Round 11
// baseline (423.803 us; speedup 1.0000x reference)
//
#include <hip/hip_runtime.h>
#include <math.h>

// ---------------------------------------------------------------------------
// Problem constants (bs=256, in_feat=48, d_model=512, dct_n=10, input_n=50,
// output_n=25, KERNEL=10, HEADS=4, vl=35, vn=16)
// ---------------------------------------------------------------------------
static constexpr float BN_SCALE_F = 0.9999950000374997f;

typedef __bf16 bf16;
typedef bf16 bf16x8 __attribute__((ext_vector_type(8)));
typedef bf16 bf16x4 __attribute__((ext_vector_type(4)));
typedef float floatx4 __attribute__((ext_vector_type(4)));

#define GLOBAL_AS __attribute__((address_space(1)))
#define LDS_AS __attribute__((address_space(3)))

enum { BM_SRC = 0, BM_R1K = 1, BM_PLAIN = 3 };

__device__ __forceinline__ float tanh_fast(float x) {
    const float e = __expf(2.f * x);
    return 1.f - 2.f / (e + 1.f);
}

// ---------------- mega prep -------------------------------------------------
__device__ __forceinline__ void d_trw1(int id, const float* w, bf16* wt) {
    if (id < 4 * 512 * 320) {
        int ho = id / 320, c = id % 320;
        float v = (c < 288) ? w[(long)ho * 288 + (c % 48) * 6 + (c / 48)] * 1e-3f : 0.f;
        wt[id] = (bf16)v;
    }
}
__global__ __launch_bounds__(256) void k_prep(
    const float* __restrict__ src, const float* __restrict__ cq1,
    const float* __restrict__ ck1, const float* __restrict__ cq2,
    const float* __restrict__ ck2, const float* __restrict__ gbw,
    const float* __restrict__ giw, float* __restrict__ dct10,
    bf16* __restrict__ srcbf, bf16* __restrict__ w1tq, bf16* __restrict__ w1tk,
    bf16* __restrict__ w2tq, bf16* __restrict__ w2tk, bf16* __restrict__ gbwt,
    bf16* __restrict__ giwP) {
    __shared__ float lds[4160];
    int bb = blockIdx.x;
    const int t = threadIdx.x;
    if (bb < 2) {
        int id = bb * 256 + t;
        if (id < 350) {
            int k = id / 35, i = id % 35;
            double w = (k == 0) ? sqrt(1.0 / 35.0) : sqrt(2.0 / 35.0);
            dct10[id] = (float)(w * cos(3.14159265358979323846 * (i + 0.5) * k / 35.0));
        }
        return;
    }
    bb -= 2;
    if (bb < 2401) {
        int id = bb * 256 + t;
        if (id < 614656) srcbf[id] = (bf16)(id < 614400 ? src[id] : 0.f);
        return;
    }
    bb -= 2401;
    if (bb < 2560) { d_trw1(bb * 256 + t, cq1, w1tq); return; }
    bb -= 2560;
    if (bb < 2560) { d_trw1(bb * 256 + t, ck1, w1tk); return; }
    bb -= 2560;
    if (bb < 4096) {
        const bool isQ = bb < 2048;
        const int ho = isQ ? bb : bb - 2048;
        const float* wrow = (isQ ? cq2 : ck2) + (long)ho * 2560;
        bf16* orow = (isQ ? w2tq : w2tk) + (long)ho * 2560;
        for (int j = t; j < 2560; j += 256) lds[j] = wrow[j];
        __syncthreads();
        for (int c = t; c < 2560; c += 256) {
            const int k = c >> 9, ii = c & 511;
            orow[c] = (bf16)lds[ii * 5 + k];
        }
        return;
    }
    bb -= 4096;
    if (bb < 256) {
        const int s = bb >> 6, tile = bb & 63;
        const int tr = tile >> 3, tc = tile & 7;
        const float* in = gbw + (long)s * 262144;
        bf16* o = gbwt + (long)s * 262144;
#pragma unroll
        for (int r = 0; r < 16; ++r) {
            const int kl = (t >> 6) * 16 + r, ml = t & 63;
            lds[kl * 65 + ml] = in[(long)(tr * 64 + kl) * 512 + tc * 64 + ml];
        }
        __syncthreads();
#pragma unroll
        for (int r = 0; r < 16; ++r) {
            const int ml = (t >> 6) * 16 + r, kl = t & 63;
            o[(long)(tc * 64 + ml) * 512 + tr * 64 + kl] = (bf16)lds[kl * 65 + ml];
        }
        return;
    }
    bb -= 256;
    {
        int id = bb * 256 + t;
        if (id < 512 * 64) {
            int f = id >> 6, k = id & 63;
            giwP[id] = (bf16)(k < 20 ? giw[k * 512 + f] : 0.f);
        }
    }
}

// ---------------- dual-branch GEMM for conv1 (padded grid) -------------------
struct GP {
    const bf16* A;
    const bf16* B;
    bf16* C;
    int NT;
    int toff;
    int nTiles;
    long aStr, bStr, cStr;
};
template <int BM1, int BM2>
__global__ __launch_bounds__(256) void mgemm2(GP p1, GP p2, const int splitX,
                                              const int M, const int K) {
    const bool first = (int)blockIdx.x < splitX;
    const GP p = first ? p1 : p2;
    const int bx = first ? (int)blockIdx.x : (int)blockIdx.x - splitX;
    if (bx >= p.nTiles) return;
    __shared__ bf16 As[128 * 64];
    __shared__ bf16 Bs[128 * 64];
    const int tid = threadIdx.x;
    const int wave = tid >> 6;
    const int lane = tid & 63;
    const int wm = (wave & 1) << 6;
    const int wn = (wave >> 1) << 6;
    const int m0 = blockIdx.y * 128;
    const int n0 = bx * 128;
    const bf16* A = p.A + (long)blockIdx.z * p.aStr;
    const bf16* B = p.B + (long)blockIdx.z * p.bStr;

    const int srow = lane >> 3;
    const int gch = (lane & 7) ^ srow;
    const bf16* aptr[4];
    const bf16* bptr[4];
#pragma unroll
    for (int i = 0; i < 4; ++i) {
        const int ar = wave * 32 + i * 8 + srow;
        aptr[i] = A + (long)(m0 + ar) * K + gch * 8;
        const int n = n0 + ar;
        long bbase;
        const bool isSrc = first ? (BM1 == BM_SRC) : (BM2 == BM_SRC);
        if (isSrc)
            bbase = (long)(n / p.NT) * 2400 + (long)((n % p.NT) + p.toff) * 48;
        else
            bbase = (long)n * K;
        bptr[i] = B + bbase + gch * 8;
    }
    const int ldsOff = wave * 32 * 64;

    floatx4 acc[4][4];
#pragma unroll
    for (int j = 0; j < 4; ++j)
#pragma unroll
        for (int i = 0; i < 4; ++i) acc[j][i] = (floatx4){0.f, 0.f, 0.f, 0.f};

    const int fr = lane & 15;
    const int fq = lane >> 4;
    const int fx = lane & 7;

    for (int k0 = 0; k0 < K; k0 += 64) {
#pragma unroll
        for (int i = 0; i < 4; ++i) {
            __builtin_amdgcn_global_load_lds(
                (const GLOBAL_AS void*)(aptr[i] + k0),
                (LDS_AS void*)(As + ldsOff + i * 512), 16, 0, 0);
            __builtin_amdgcn_global_load_lds(
                (const GLOBAL_AS void*)(bptr[i] + k0),
                (LDS_AS void*)(Bs + ldsOff + i * 512), 16, 0, 0);
        }
        __syncthreads();
#pragma unroll
        for (int kk = 0; kk < 2; ++kk) {
            bf16x8 af[4], bfr[4];
#pragma unroll
            for (int im = 0; im < 4; ++im)
                af[im] = *(const bf16x8*)(As + (wm + im * 16 + fr) * 64 +
                                          ((((kk << 2) + fq) ^ fx) << 3));
#pragma unroll
            for (int in = 0; in < 4; ++in)
                bfr[in] = *(const bf16x8*)(Bs + (wn + in * 16 + fr) * 64 +
                                           ((((kk << 2) + fq) ^ fx) << 3));
#pragma unroll
            for (int in = 0; in < 4; ++in)
#pragma unroll
                for (int im = 0; im < 4; ++im)
                    acc[in][im] = __builtin_amdgcn_mfma_f32_16x16x32_bf16(
                        af[im], bfr[in], acc[in][im], 0, 0, 0);
        }
        __syncthreads();
    }
#pragma unroll
    for (int in = 0; in < 4; ++in) {
        const long n = n0 + wn + in * 16 + fr;
#pragma unroll
        for (int im = 0; im < 4; ++im) {
            floatx4 v = acc[in][im];
            const long m = m0 + wm + im * 16 + (fq << 2);
            v.x = fmaxf(v.x, 0.f);
            v.y = fmaxf(v.y, 0.f);
            v.z = fmaxf(v.z, 0.f);
            v.w = fmaxf(v.w, 0.f);
            bf16* C = p.C + (long)blockIdx.z * p.cStr + n * M + m;
            bf16x4 ov;
            ov[0] = (bf16)v.x;
            ov[1] = (bf16)v.y;
            ov[2] = (bf16)v.z;
            ov[3] = (bf16)v.w;
            *(bf16x4*)C = ov;
        }
    }
}

// ---------------- conv2 K+Q fused (544 blocks, K swizzled for XCD L2) --------
__global__ __launch_bounds__(256) void k_conv2(
    const bf16* __restrict__ w2tk, const bf16* __restrict__ r1k,
    bf16* __restrict__ keyh, const bf16* __restrict__ w2tq,
    const bf16* __restrict__ r1q, bf16* __restrict__ qh) {
    const int M = 512, K = 2560;
    int bx, by, bz;
    const bf16 *A, *B;
    bf16* C;
    bool r1kMode;
    long aStr, bStr, cStr;
    {
        const int i = blockIdx.x;
        if (i < 512) {
            const int slot = i & 7;
            bz = slot & 3;
            const int half = slot >> 2;
            const int j = i >> 3;
            bx = half * 16 + (j & 15);
            by = j >> 4;
            A = w2tk; B = r1k; C = keyh; r1kMode = true;
            aStr = 512L * 2560; bStr = 2621440L; cStr = 2097152L;
        } else {
            const int j = i - 512;
            bx = j & 1;
            by = (j >> 1) & 3;
            bz = j >> 3;
            A = w2tq; B = r1q; C = qh; r1kMode = false;
            aStr = 512L * 2560; bStr = 655360L; cStr = 131072L;
        }
    }
    __shared__ bf16 As[128 * 64];
    __shared__ bf16 Bs[128 * 64];
    const int tid = threadIdx.x;
    const int wave = tid >> 6;
    const int lane = tid & 63;
    const int wm = (wave & 1) << 6;
    const int wn = (wave >> 1) << 6;
    const int m0 = by * 128;
    const int n0 = bx * 128;
    A += (long)bz * aStr;
    B += (long)bz * bStr;

    const int srow = lane >> 3;
    const int gch = (lane & 7) ^ srow;
    const bf16* aptr[4];
    const bf16* bptr[4];
#pragma unroll
    for (int i = 0; i < 4; ++i) {
        const int ar = wave * 32 + i * 8 + srow;
        aptr[i] = A + (long)(m0 + ar) * K + gch * 8;
        const int n = n0 + ar;
        const long bbase = r1kMode ? (long)((n >> 4) * 20 + (n & 15)) * 512
                                   : (long)n * K;
        bptr[i] = B + bbase + gch * 8;
    }
    const int ldsOff = wave * 32 * 64;

    floatx4 acc[4][4];
#pragma unroll
    for (int j = 0; j < 4; ++j)
#pragma unroll
        for (int i = 0; i < 4; ++i) acc[j][i] = (floatx4){0.f, 0.f, 0.f, 0.f};

    const int fr = lane & 15;
    const int fq = lane >> 4;
    const int fx = lane & 7;

    for (int k0 = 0; k0 < K; k0 += 64) {
#pragma unroll
        for (int i = 0; i < 4; ++i) {
            __builtin_amdgcn_global_load_lds(
                (const GLOBAL_AS void*)(aptr[i] + k0),
                (LDS_AS void*)(As + ldsOff + i * 512), 16, 0, 0);
            __builtin_amdgcn_global_load_lds(
                (const GLOBAL_AS void*)(bptr[i] + k0),
                (LDS_AS void*)(Bs + ldsOff + i * 512), 16, 0, 0);
        }
        __syncthreads();
#pragma unroll
        for (int kk = 0; kk < 2; ++kk) {
            bf16x8 af[4], bfr[4];
#pragma unroll
            for (int im = 0; im < 4; ++im)
                af[im] = *(const bf16x8*)(As + (wm + im * 16 + fr) * 64 +
                                          ((((kk << 2) + fq) ^ fx) << 3));
#pragma unroll
            for (int in = 0; in < 4; ++in)
                bfr[in] = *(const bf16x8*)(Bs + (wn + in * 16 + fr) * 64 +
                                           ((((kk << 2) + fq) ^ fx) << 3));
#pragma unroll
            for (int in = 0; in < 4; ++in)
#pragma unroll
                for (int im = 0; im < 4; ++im)
                    acc[in][im] = __builtin_amdgcn_mfma_f32_16x16x32_bf16(
                        af[im], bfr[in], acc[in][im], 0, 0, 0);
        }
        __syncthreads();
    }
#pragma unroll
    for (int in = 0; in < 4; ++in) {
        const long n = n0 + wn + in * 16 + fr;
#pragma unroll
        for (int im = 0; im < 4; ++im) {
            floatx4 v = acc[in][im];
            const long m = m0 + wm + im * 16 + (fq << 2);
            v.x = fmaxf(v.x, 0.f);
            v.y = fmaxf(v.y, 0.f);
            v.z = fmaxf(v.z, 0.f);
            v.w = fmaxf(v.w, 0.f);
            bf16* Cp = C + (long)bz * cStr + n * M + m;
            bf16x4 ov;
            ov[0] = (bf16)v.x;
            ov[1] = (bf16)v.y;
            ov[2] = (bf16)v.z;
            ov[3] = (bf16)v.w;
            *(bf16x4*)Cp = ov;
        }
    }
}

// ---------------- fused attention block (one block per batch b) --------------
__global__ __launch_bounds__(512) void k_att(
    const bf16* __restrict__ qh, const bf16* __restrict__ keyh,
    const float* __restrict__ src, const float* __restrict__ dct10,
    const float* __restrict__ lw, const float* __restrict__ lb,
    const float* __restrict__ gia, float* __restrict__ dctin,
    bf16* __restrict__ z0) {
    const int b = blockIdx.x;
    const int t = threadIdx.x;
    __shared__ float BIG[9216];
    __shared__ float WD[2400];
    __shared__ float D[350];
    __shared__ float L[1920];
    __shared__ float dinS[960];
    __shared__ float sS[64];
    __shared__ float awS[64];

    {
        const int g = t >> 3, lane = t & 7;
        const int h = g >> 4, tt = g & 15;
        const bf16* q = qh + ((long)h * 256 + b) * 512 + lane * 64;
        const bf16* kr = keyh + (long)h * 2097152 + ((long)b * 16 + tt) * 512 + lane * 64;
        float p = 0.f;
#pragma unroll
        for (int i = 0; i < 8; ++i) {
            const bf16x8 qv = *(const bf16x8*)(q + i * 8);
            const bf16x8 kv = *(const bf16x8*)(kr + i * 8);
#pragma unroll
            for (int j = 0; j < 8; ++j) p = fmaf((float)qv[j], (float)kv[j], p);
        }
        p += __shfl_down(p, 4, 8);
        p += __shfl_down(p, 2, 8);
        p += __shfl_down(p, 1, 8);
        if (lane == 0) sS[g] = p + 1e-15f;
    }
    for (int i = t; i < 2400; i += 512) WD[i] = src[(long)b * 2400 + i];
    for (int i = t; i < 350; i += 512) D[i] = dct10[i];
    __syncthreads();
    if (t < 4) {
        float s = 0.f;
#pragma unroll
        for (int k = 0; k < 16; ++k) s += sS[t * 16 + k];
        const float inv = 1.f / s;
#pragma unroll
        for (int k = 0; k < 16; ++k) awS[t * 16 + k] = sS[t * 16 + k] * inv;
    }
    __syncthreads();
    for (int p = 0; p < 15; ++p) {
        const int idx = t + p * 512;
        const int n = idx / 480, j = idx % 480;
        const int f = j / 10, d = j % 10;
        float acc = 0.f;
#pragma unroll
        for (int v = 0; v < 35; ++v)
            acc = fmaf(D[d * 35 + v], WD[(n + v) * 48 + f], acc);
        BIG[idx] = acc;
    }
    __syncthreads();
    for (int p = 0; p < 4; ++p) {
        const int idx = t + p * 512;
        if (idx < 1920) {
            const int h = idx / 480, j = idx % 480;
            float acc = 0.f;
#pragma unroll
            for (int k = 0; k < 16; ++k)
                acc = fmaf(awS[h * 16 + k], BIG[k * 480 + j], acc);
            L[idx] = acc;
        }
    }
    if (t < 480) {
        const int f = t / 10, d = t % 10;
        float acc = 0.f;
#pragma unroll
        for (int v = 0; v < 10; ++v)
            acc = fmaf(D[d * 35 + v], WD[(40 + v) * 48 + f], acc);
        float cs = 0.f;
#pragma unroll
        for (int v = 10; v < 35; ++v) cs += D[d * 35 + v];
        acc = fmaf(cs, WD[49 * 48 + f], acc);
        dinS[f * 20 + d] = acc;
        dctin[(long)b * 960 + f * 20 + d] = acc;
    }
    __syncthreads();
    for (int i = t; i < 9216; i += 512) BIG[i] = lw[i];
    for (int i = t; i < 2304; i += 512) WD[i] = gia[i];
    __syncthreads();
    if (t < 480) {
        const int n = t / 10, d = t % 10;
        float acc = lb[n];
#pragma unroll
        for (int h = 0; h < 4; ++h)
#pragma unroll
            for (int f = 0; f < 48; ++f)
                acc = fmaf(BIG[n * 192 + h * 48 + f], L[h * 480 + f * 10 + d], acc);
        dinS[n * 20 + 10 + d] = acc;
        dctin[(long)b * 960 + n * 20 + 10 + d] = acc;
    }
    __syncthreads();
    for (int p = 0; p < 2; ++p) {
        const int idx = t + p * 512;
        if (idx < 960) {
            const int n = idx / 20, d = idx % 20;
            float acc = 0.f;
#pragma unroll
            for (int m = 0; m < 48; ++m)
                acc = fmaf(WD[n * 48 + m], dinS[m * 20 + d], acc);
            z0[((long)b * 48 + n) * 64 + d] = (bf16)acc;
        }
    }
    for (int i = t; i < 2112; i += 512) {
        const int n = i / 44, c = 20 + i % 44;
        z0[((long)b * 48 + n) * 64 + c] = (bf16)0.f;
    }
}

// ---------------- GCN mega-kernel (1024 threads, 16 waves) -------------------
// MFMA matmul with depth-4 ring prefetch of W (L2 latency ~200-500cyc vs ~40cyc
// of math/iter: round-10 depth-1 dbuf left it exposed — MfmaUtil stuck at 9.6%).
__device__ __forceinline__ void gcn_matmul(const bf16* zS, const bf16* Bg,
                                           const int K, const float* bias,
                                           const bf16* resS, bf16* outS,
                                           const int wave, const int lane) {
    const int fr = lane & 15, fq = lane >> 4;
    const int f0 = wave * 32;
    floatx4 acc[3][2];
#pragma unroll
    for (int it = 0; it < 3; ++it)
#pragma unroll
        for (int jt = 0; jt < 2; ++jt) acc[it][jt] = (floatx4){0.f, 0.f, 0.f, 0.f};
    const bf16* bp0 = Bg + (long)(f0 + fr) * K + fq * 8;
    const bf16* bp1 = bp0 + 16 * (long)K;
    bf16x8 rb0[4], rb1[4];
#pragma unroll
    for (int i = 0; i < 4; ++i) {
        int kk = i * 32;
        if (kk > K - 32) kk = K - 32;
        rb0[i] = *(const bf16x8*)(bp0 + kk);
        rb1[i] = *(const bf16x8*)(bp1 + kk);
    }
    int slot = 0;
#pragma unroll 4
    for (int k0 = 0; k0 < K; k0 += 32) {
        const bf16x8 bc0 = rb0[slot];
        const bf16x8 bc1 = rb1[slot];
        int kn = k0 + 128;
        if (kn > K - 32) kn = K - 32;
        rb0[slot] = *(const bf16x8*)(bp0 + kn);
        rb1[slot] = *(const bf16x8*)(bp1 + kn);
        slot = (slot + 1) & 3;
        bf16x8 af[3];
#pragma unroll
        for (int it = 0; it < 3; ++it)
            af[it] = *(const bf16x8*)(zS + (it * 16 + fr) * 520 + k0 + fq * 8);
#pragma unroll
        for (int it = 0; it < 3; ++it) {
            acc[it][0] = __builtin_amdgcn_mfma_f32_16x16x32_bf16(af[it], bc0,
                                                                acc[it][0], 0, 0, 0);
            acc[it][1] = __builtin_amdgcn_mfma_f32_16x16x32_bf16(af[it], bc1,
                                                                acc[it][1], 0, 0, 0);
        }
    }
#pragma unroll
    for (int jt = 0; jt < 2; ++jt) {
        const int f = f0 + jt * 16 + fr;
        const float bv = bias[f];
#pragma unroll
        for (int it = 0; it < 3; ++it)
#pragma unroll
            for (int r = 0; r < 4; ++r) {
                const int irow = it * 16 + fq * 4 + r;
                float v = tanh_fast((acc[it][jt][r] + bv) * BN_SCALE_F);
                if (resS) v += (float)resS[irow * 520 + f];
                outS[irow * 520 + f] = (bf16)v;
            }
    }
}

// VALU attmul: Z[i][f] = sum_m attF[i*48+m] * Y[m][f].
// Per-wave ig uniform -> att reads broadcast (free); Y reads consecutive b128
// (conflict-free); replaces round-10's 32 scalar gathers/lane (4.6M conflicts).
__device__ __forceinline__ void gcn_attmul(const float* attF, const bf16* yS,
                                           bf16* zS, const int t) {
    const int fg = t & 63;   // 64 f-groups of 8
    const int ig = t >> 6;   // 16 i-groups of 3
    float acc[3][8];
#pragma unroll
    for (int i = 0; i < 3; ++i)
#pragma unroll
        for (int j = 0; j < 8; ++j) acc[i][j] = 0.f;
    const float* a0 = attF + (ig * 3) * 48;
#pragma unroll 4
    for (int m = 0; m < 48; ++m) {
        const bf16x8 yv = *(const bf16x8*)(yS + m * 520 + fg * 8);
        float yf[8];
#pragma unroll
        for (int j = 0; j < 8; ++j) yf[j] = (float)yv[j];
        const float a_0 = a0[m];
        const float a_1 = a0[48 + m];
        const float a_2 = a0[96 + m];
#pragma unroll
        for (int j = 0; j < 8; ++j) {
            acc[0][j] = fmaf(a_0, yf[j], acc[0][j]);
            acc[1][j] = fmaf(a_1, yf[j], acc[1][j]);
            acc[2][j] = fmaf(a_2, yf[j], acc[2][j]);
        }
    }
#pragma unroll
    for (int i = 0; i < 3; ++i) {
        bf16x8 o;
#pragma unroll
        for (int j = 0; j < 8; ++j) o[j] = (bf16)acc[i][j];
        *(bf16x8*)(zS + (ig * 3 + i) * 520 + fg * 8) = o;
    }
}

__global__ __launch_bounds__(1024) void k_gcn(
    const bf16* __restrict__ z0, const bf16* __restrict__ giwP,
    const float* __restrict__ gib, const bf16* __restrict__ gbwt,
    const float* __restrict__ gba, const float* __restrict__ gbb,
    const float* __restrict__ goa, const float* __restrict__ gow,
    const float* __restrict__ gob, const float* __restrict__ dctin,
    const float* __restrict__ dct10, float* __restrict__ out) {
    const int b = blockIdx.x;
    const int t = threadIdx.x;
    const int wave = t >> 6, lane = t & 63;
    __shared__ __align__(16) bf16 yaS[48 * 520];
    __shared__ __align__(16) bf16 ybS[48 * 520];
    __shared__ __align__(16) bf16 zS[48 * 520];
    __shared__ __align__(16) float attF[2304];

    if (t < 384) {
        const int r = t >> 3, c = t & 7;
        *(bf16x8*)(zS + r * 520 + c * 8) =
            *(const bf16x8*)(z0 + ((long)b * 48 + r) * 64 + c * 8);
    }
    __syncthreads();
    gcn_matmul(zS, giwP, 64, gib, nullptr, yaS, wave, lane);
    __syncthreads();

#pragma unroll
    for (int l = 0; l < 4; ++l) {
        bf16* Yin = (l == 0 || l == 3) ? yaS : ybS;
        bf16* Yout = (l < 2) ? ybS : yaS;
        bf16* Res = (l == 1) ? yaS : (l == 3 ? ybS : nullptr);
        for (int i = t; i < 2304; i += 1024) attF[i] = gba[l * 2304 + i];
        __syncthreads();
        gcn_attmul(attF, Yin, zS, t);
        __syncthreads();
        gcn_matmul(zS, gbwt + (long)l * 262144, 512, gbb + l * 512, Res, Yout,
                   wave, lane);
        __syncthreads();
    }
    // ---- gc_out + iDCT (final Y = yaS) ----
    bf16* GS = zS;                              // [20][520] gow^T
    float* goaS = (float*)((char*)zS + 24576);  // 2304 f32
    float* Df = attF;                           // 350 f32
    float* T2 = (float*)ybS;                    // 960 f32
    float* dS = ((float*)ybS) + 1024;           // 960 f32
    for (int i = t; i < 10240; i += 1024) {
        const int d = i >> 9, k = i & 511;
        GS[d * 520 + k] = (bf16)gow[k * 20 + d];
    }
    for (int i = t; i < 2304; i += 1024) goaS[i] = goa[i];
    if (t < 350) Df[t] = dct10[t];
    __syncthreads();
    for (int idx = t; idx < 960; idx += 1024) {
        const int m = idx / 20, d = idx % 20;
        float acc = 0.f;
        const bf16* yr = yaS + m * 520;
        const bf16* gr = GS + d * 520;
#pragma unroll 8
        for (int k8 = 0; k8 < 64; ++k8) {
            const bf16x8 yv = *(const bf16x8*)(yr + k8 * 8);
            const bf16x8 gv = *(const bf16x8*)(gr + k8 * 8);
#pragma unroll
            for (int j = 0; j < 8; ++j) acc = fmaf((float)yv[j], (float)gv[j], acc);
        }
        T2[idx] = acc;
    }
    __syncthreads();
    for (int idx = t; idx < 960; idx += 1024) {
        const int n = idx / 20, d = idx % 20;
        float acc = gob[d] + dctin[(long)b * 960 + idx];
#pragma unroll
        for (int m = 0; m < 48; ++m)
            acc = fmaf(goaS[n * 48 + m], T2[m * 20 + d], acc);
        dS[idx] = acc;
    }
    __syncthreads();
    for (int e = t; e < 1680; e += 1024) {
        const int v = e / 48, n = e % 48;
        float acc = 0.f;
#pragma unroll
        for (int d = 0; d < 10; ++d)
            acc = fmaf(Df[d * 35 + v], dS[n * 20 + d], acc);
        out[(long)b * 1680 + e] = acc;
    }
}

// ---------------------------------------------------------------------------
// Workspace (BYTE offsets). keyh bf16 (16.8 MB) aliases WS_T; z0 at WS_T+17MB.
// ---------------------------------------------------------------------------
static constexpr size_t WS_DCT10 = 0;
static constexpr size_t WS_ATTW = 1536;
static constexpr size_t WS_QH = WS_ATTW + 65536;
static constexpr size_t WS_DCTIN = WS_QH + 2097152;
static constexpr size_t WS_DCTOUT = WS_DCTIN + 983040;
static constexpr size_t WS_SRCVAL = WS_DCTOUT + 983040;
static constexpr size_t WS_PAD0 = WS_SRCVAL + 7864320;
static constexpr size_t WS_SRCBF = WS_PAD0 + 8388608;
static constexpr size_t WS_W1TQ = WS_SRCBF + 1229824;
static constexpr size_t WS_W1TK = WS_W1TQ + 1310720;
static constexpr size_t WS_W2TQ = WS_W1TK + 1310720;
static constexpr size_t WS_W2TK = WS_W2TQ + 10485760;
static constexpr size_t WS_GBWT = WS_W2TK + 10485760;
static constexpr size_t WS_R1K = WS_GBWT + 2097152;
static constexpr size_t WS_R1Q = WS_R1K + 20971520;
static constexpr size_t WS_T = WS_R1Q + 5242880;
static constexpr size_t WS_GIWP = WS_T + 50331648;
static constexpr size_t WS_KEYH = WS_T;
static constexpr size_t WS_Z0 = WS_T + 17825792;

extern "C" void kernel_launch(void* const* d_in, const int* in_sizes, int n_in,
                              void* d_out, int out_size, void* d_ws,
                              size_t ws_size, hipStream_t stream) {
    const float* src = (const float*)d_in[0];
    const float* cq1 = (const float*)d_in[1];
    const float* cq2 = (const float*)d_in[2];
    const float* ck1 = (const float*)d_in[3];
    const float* ck2 = (const float*)d_in[4];
    const float* lw = (const float*)d_in[5];
    const float* lb = (const float*)d_in[6];
    const float* giw = (const float*)d_in[7];
    const float* gia = (const float*)d_in[8];
    const float* gib = (const float*)d_in[9];
    const float* gbw = (const float*)d_in[10];
    const float* gba = (const float*)d_in[11];
    const float* gbb = (const float*)d_in[12];
    const float* gow = (const float*)d_in[13];
    const float* goa = (const float*)d_in[14];
    const float* gob = (const float*)d_in[15];
    float* out = (float*)d_out;
    char* ws = (char*)d_ws;

    float* dct10 = (float*)(ws + WS_DCT10);
    bf16* qh = (bf16*)(ws + WS_QH);
    float* dctin = (float*)(ws + WS_DCTIN);
    bf16* keyh = (bf16*)(ws + WS_KEYH);
    bf16* srcbf = (bf16*)(ws + WS_SRCBF);
    bf16* w1tq = (bf16*)(ws + WS_W1TQ);
    bf16* w1tk = (bf16*)(ws + WS_W1TK);
    bf16* w2tq = (bf16*)(ws + WS_W2TQ);
    bf16* w2tk = (bf16*)(ws + WS_W2TK);
    bf16* gbwt = (bf16*)(ws + WS_GBWT);
    bf16* r1k = (bf16*)(ws + WS_R1K);
    bf16* r1q = (bf16*)(ws + WS_R1Q);
    bf16* giwP = (bf16*)(ws + WS_GIWP);
    bf16* z0 = (bf16*)(ws + WS_Z0);

    // 1. all prep in one dispatch (tiled transposes)
    k_prep<<<12003, 256, 0, stream>>>(src, cq1, ck1, cq2, ck2, gbw, giw, dct10,
                                      srcbf, w1tq, w1tk, w2tq, w2tk, gbwt, giwP);

    // 2. conv1 K+Q fused, gridDim.x padded to 56
    {
        GP pk{w1tk, srcbf, r1k, 20, 0, 40, 512L * 320, 0L, 5120L * 512};
        GP pq{w1tq, srcbf, r1q, 5, 40, 10, 512L * 320, 0L, 1280L * 512};
        mgemm2<BM_SRC, BM_SRC><<<dim3(56, 4, 4), 256, 0, stream>>>(pk, pq, 40,
                                                                   512, 320);
    }
    // 3. conv2 K+Q in one 544-block dispatch (K swizzled)
    k_conv2<<<544, 256, 0, stream>>>(w2tk, r1k, keyh, w2tq, r1q, qh);

    // 4. fused attention block -> dctin (fp32), z0 (bf16)
    k_att<<<256, 512, 0, stream>>>(qh, keyh, src, dct10, lw, lb, gia, dctin, z0);

    // 5. whole GCN in one dispatch (1024 threads, ring-prefetched W)
    k_gcn<<<256, 1024, 0, stream>>>(z0, giwP, gib, gbwt, gba, gbb, goa, gow,
                                    gob, dctin, dct10, out);
}

// Round 12
// 369.690 us; speedup vs baseline: 1.1464x; 1.1464x over previous
//
#include <hip/hip_runtime.h>
#include <math.h>

// ---------------------------------------------------------------------------
// Problem constants (bs=256, in_feat=48, d_model=512, dct_n=10, input_n=50,
// output_n=25, KERNEL=10, HEADS=4, vl=35, vn=16)
// ---------------------------------------------------------------------------
static constexpr float BN_SCALE_F = 0.9999950000374997f;

typedef __bf16 bf16;
typedef bf16 bf16x8 __attribute__((ext_vector_type(8)));
typedef bf16 bf16x4 __attribute__((ext_vector_type(4)));
typedef float floatx4 __attribute__((ext_vector_type(4)));

#define GLOBAL_AS __attribute__((address_space(1)))
#define LDS_AS __attribute__((address_space(3)))

enum { BM_SRC = 0, BM_R1K = 1, BM_PLAIN = 3 };

__device__ __forceinline__ float tanh_fast(float x) {
    const float e = __expf(2.f * x);
    return 1.f - 2.f / (e + 1.f);
}

// ---------------- mega prep -------------------------------------------------
__device__ __forceinline__ void d_trw1(int id, const float* w, bf16* wt) {
    if (id < 4 * 512 * 320) {
        int ho = id / 320, c = id % 320;
        float v = (c < 288) ? w[(long)ho * 288 + (c % 48) * 6 + (c / 48)] * 1e-3f : 0.f;
        wt[id] = (bf16)v;
    }
}
__global__ __launch_bounds__(256) void k_prep(
    const float* __restrict__ src, const float* __restrict__ cq1,
    const float* __restrict__ ck1, const float* __restrict__ cq2,
    const float* __restrict__ ck2, const float* __restrict__ gbw,
    const float* __restrict__ giw, float* __restrict__ dct10,
    bf16* __restrict__ srcbf, bf16* __restrict__ w1tq, bf16* __restrict__ w1tk,
    bf16* __restrict__ w2tq, bf16* __restrict__ w2tk, bf16* __restrict__ gbwt,
    bf16* __restrict__ giwP) {
    __shared__ float lds[4160];
    int bb = blockIdx.x;
    const int t = threadIdx.x;
    if (bb < 2) {
        int id = bb * 256 + t;
        if (id < 350) {
            int k = id / 35, i = id % 35;
            double w = (k == 0) ? sqrt(1.0 / 35.0) : sqrt(2.0 / 35.0);
            dct10[id] = (float)(w * cos(3.14159265358979323846 * (i + 0.5) * k / 35.0));
        }
        return;
    }
    bb -= 2;
    if (bb < 2401) {
        int id = bb * 256 + t;
        if (id < 614656) srcbf[id] = (bf16)(id < 614400 ? src[id] : 0.f);
        return;
    }
    bb -= 2401;
    if (bb < 2560) { d_trw1(bb * 256 + t, cq1, w1tq); return; }
    bb -= 2560;
    if (bb < 2560) { d_trw1(bb * 256 + t, ck1, w1tk); return; }
    bb -= 2560;
    if (bb < 4096) {
        const bool isQ = bb < 2048;
        const int ho = isQ ? bb : bb - 2048;
        const float* wrow = (isQ ? cq2 : ck2) + (long)ho * 2560;
        bf16* orow = (isQ ? w2tq : w2tk) + (long)ho * 2560;
        for (int j = t; j < 2560; j += 256) lds[j] = wrow[j];
        __syncthreads();
        for (int c = t; c < 2560; c += 256) {
            const int k = c >> 9, ii = c & 511;
            orow[c] = (bf16)lds[ii * 5 + k];
        }
        return;
    }
    bb -= 4096;
    if (bb < 256) {
        const int s = bb >> 6, tile = bb & 63;
        const int tr = tile >> 3, tc = tile & 7;
        const float* in = gbw + (long)s * 262144;
        bf16* o = gbwt + (long)s * 262144;
#pragma unroll
        for (int r = 0; r < 16; ++r) {
            const int kl = (t >> 6) * 16 + r, ml = t & 63;
            lds[kl * 65 + ml] = in[(long)(tr * 64 + kl) * 512 + tc * 64 + ml];
        }
        __syncthreads();
#pragma unroll
        for (int r = 0; r < 16; ++r) {
            const int ml = (t >> 6) * 16 + r, kl = t & 63;
            o[(long)(tc * 64 + ml) * 512 + tr * 64 + kl] = (bf16)lds[kl * 65 + ml];
        }
        return;
    }
    bb -= 256;
    {
        int id = bb * 256 + t;
        if (id < 512 * 64) {
            int f = id >> 6, k = id & 63;
            giwP[id] = (bf16)(k < 20 ? giw[k * 512 + f] : 0.f);
        }
    }
}

// ---------------- dual-branch GEMM for conv1 (padded grid) -------------------
struct GP {
    const bf16* A;
    const bf16* B;
    bf16* C;
    int NT;
    int toff;
    int nTiles;
    long aStr, bStr, cStr;
};
template <int BM1, int BM2>
__global__ __launch_bounds__(256) void mgemm2(GP p1, GP p2, const int splitX,
                                              const int M, const int K) {
    const bool first = (int)blockIdx.x < splitX;
    const GP p = first ? p1 : p2;
    const int bx = first ? (int)blockIdx.x : (int)blockIdx.x - splitX;
    if (bx >= p.nTiles) return;
    __shared__ bf16 As[128 * 64];
    __shared__ bf16 Bs[128 * 64];
    const int tid = threadIdx.x;
    const int wave = tid >> 6;
    const int lane = tid & 63;
    const int wm = (wave & 1) << 6;
    const int wn = (wave >> 1) << 6;
    const int m0 = blockIdx.y * 128;
    const int n0 = bx * 128;
    const bf16* A = p.A + (long)blockIdx.z * p.aStr;
    const bf16* B = p.B + (long)blockIdx.z * p.bStr;

    const int srow = lane >> 3;
    const int gch = (lane & 7) ^ srow;
    const bf16* aptr[4];
    const bf16* bptr[4];
#pragma unroll
    for (int i = 0; i < 4; ++i) {
        const int ar = wave * 32 + i * 8 + srow;
        aptr[i] = A + (long)(m0 + ar) * K + gch * 8;
        const int n = n0 + ar;
        long bbase;
        const bool isSrc = first ? (BM1 == BM_SRC) : (BM2 == BM_SRC);
        if (isSrc)
            bbase = (long)(n / p.NT) * 2400 + (long)((n % p.NT) + p.toff) * 48;
        else
            bbase = (long)n * K;
        bptr[i] = B + bbase + gch * 8;
    }
    const int ldsOff = wave * 32 * 64;

    floatx4 acc[4][4];
#pragma unroll
    for (int j = 0; j < 4; ++j)
#pragma unroll
        for (int i = 0; i < 4; ++i) acc[j][i] = (floatx4){0.f, 0.f, 0.f, 0.f};

    const int fr = lane & 15;
    const int fq = lane >> 4;
    const int fx = lane & 7;

    for (int k0 = 0; k0 < K; k0 += 64) {
#pragma unroll
        for (int i = 0; i < 4; ++i) {
            __builtin_amdgcn_global_load_lds(
                (const GLOBAL_AS void*)(aptr[i] + k0),
                (LDS_AS void*)(As + ldsOff + i * 512), 16, 0, 0);
            __builtin_amdgcn_global_load_lds(
                (const GLOBAL_AS void*)(bptr[i] + k0),
                (LDS_AS void*)(Bs + ldsOff + i * 512), 16, 0, 0);
        }
        __syncthreads();
#pragma unroll
        for (int kk = 0; kk < 2; ++kk) {
            bf16x8 af[4], bfr[4];
#pragma unroll
            for (int im = 0; im < 4; ++im)
                af[im] = *(const bf16x8*)(As + (wm + im * 16 + fr) * 64 +
                                          ((((kk << 2) + fq) ^ fx) << 3));
#pragma unroll
            for (int in = 0; in < 4; ++in)
                bfr[in] = *(const bf16x8*)(Bs + (wn + in * 16 + fr) * 64 +
                                           ((((kk << 2) + fq) ^ fx) << 3));
#pragma unroll
            for (int in = 0; in < 4; ++in)
#pragma unroll
                for (int im = 0; im < 4; ++im)
                    acc[in][im] = __builtin_amdgcn_mfma_f32_16x16x32_bf16(
                        af[im], bfr[in], acc[in][im], 0, 0, 0);
        }
        __syncthreads();
    }
#pragma unroll
    for (int in = 0; in < 4; ++in) {
        const long n = n0 + wn + in * 16 + fr;
#pragma unroll
        for (int im = 0; im < 4; ++im) {
            floatx4 v = acc[in][im];
            const long m = m0 + wm + im * 16 + (fq << 2);
            v.x = fmaxf(v.x, 0.f);
            v.y = fmaxf(v.y, 0.f);
            v.z = fmaxf(v.z, 0.f);
            v.w = fmaxf(v.w, 0.f);
            bf16* C = p.C + (long)blockIdx.z * p.cStr + n * M + m;
            bf16x4 ov;
            ov[0] = (bf16)v.x;
            ov[1] = (bf16)v.y;
            ov[2] = (bf16)v.z;
            ov[3] = (bf16)v.w;
            *(bf16x4*)C = ov;
        }
    }
}

// ---------------- conv2 K+Q fused (544 blocks, K swizzled for XCD L2) --------
__global__ __launch_bounds__(256) void k_conv2(
    const bf16* __restrict__ w2tk, const bf16* __restrict__ r1k,
    bf16* __restrict__ keyh, const bf16* __restrict__ w2tq,
    const bf16* __restrict__ r1q, bf16* __restrict__ qh) {
    const int M = 512, K = 2560;
    int bx, by, bz;
    const bf16 *A, *B;
    bf16* C;
    bool r1kMode;
    long aStr, bStr, cStr;
    {
        const int i = blockIdx.x;
        if (i < 512) {
            const int slot = i & 7;
            bz = slot & 3;
            const int half = slot >> 2;
            const int j = i >> 3;
            bx = half * 16 + (j & 15);
            by = j >> 4;
            A = w2tk; B = r1k; C = keyh; r1kMode = true;
            aStr = 512L * 2560; bStr = 2621440L; cStr = 2097152L;
        } else {
            const int j = i - 512;
            bx = j & 1;
            by = (j >> 1) & 3;
            bz = j >> 3;
            A = w2tq; B = r1q; C = qh; r1kMode = false;
            aStr = 512L * 2560; bStr = 655360L; cStr = 131072L;
        }
    }
    __shared__ bf16 As[128 * 64];
    __shared__ bf16 Bs[128 * 64];
    const int tid = threadIdx.x;
    const int wave = tid >> 6;
    const int lane = tid & 63;
    const int wm = (wave & 1) << 6;
    const int wn = (wave >> 1) << 6;
    const int m0 = by * 128;
    const int n0 = bx * 128;
    A += (long)bz * aStr;
    B += (long)bz * bStr;

    const int srow = lane >> 3;
    const int gch = (lane & 7) ^ srow;
    const bf16* aptr[4];
    const bf16* bptr[4];
#pragma unroll
    for (int i = 0; i < 4; ++i) {
        const int ar = wave * 32 + i * 8 + srow;
        aptr[i] = A + (long)(m0 + ar) * K + gch * 8;
        const int n = n0 + ar;
        const long bbase = r1kMode ? (long)((n >> 4) * 20 + (n & 15)) * 512
                                   : (long)n * K;
        bptr[i] = B + bbase + gch * 8;
    }
    const int ldsOff = wave * 32 * 64;

    floatx4 acc[4][4];
#pragma unroll
    for (int j = 0; j < 4; ++j)
#pragma unroll
        for (int i = 0; i < 4; ++i) acc[j][i] = (floatx4){0.f, 0.f, 0.f, 0.f};

    const int fr = lane & 15;
    const int fq = lane >> 4;
    const int fx = lane & 7;

    for (int k0 = 0; k0 < K; k0 += 64) {
#pragma unroll
        for (int i = 0; i < 4; ++i) {
            __builtin_amdgcn_global_load_lds(
                (const GLOBAL_AS void*)(aptr[i] + k0),
                (LDS_AS void*)(As + ldsOff + i * 512), 16, 0, 0);
            __builtin_amdgcn_global_load_lds(
                (const GLOBAL_AS void*)(bptr[i] + k0),
                (LDS_AS void*)(Bs + ldsOff + i * 512), 16, 0, 0);
        }
        __syncthreads();
#pragma unroll
        for (int kk = 0; kk < 2; ++kk) {
            bf16x8 af[4], bfr[4];
#pragma unroll
            for (int im = 0; im < 4; ++im)
                af[im] = *(const bf16x8*)(As + (wm + im * 16 + fr) * 64 +
                                          ((((kk << 2) + fq) ^ fx) << 3));
#pragma unroll
            for (int in = 0; in < 4; ++in)
                bfr[in] = *(const bf16x8*)(Bs + (wn + in * 16 + fr) * 64 +
                                           ((((kk << 2) + fq) ^ fx) << 3));
#pragma unroll
            for (int in = 0; in < 4; ++in)
#pragma unroll
                for (int im = 0; im < 4; ++im)
                    acc[in][im] = __builtin_amdgcn_mfma_f32_16x16x32_bf16(
                        af[im], bfr[in], acc[in][im], 0, 0, 0);
        }
        __syncthreads();
    }
#pragma unroll
    for (int in = 0; in < 4; ++in) {
        const long n = n0 + wn + in * 16 + fr;
#pragma unroll
        for (int im = 0; im < 4; ++im) {
            floatx4 v = acc[in][im];
            const long m = m0 + wm + im * 16 + (fq << 2);
            v.x = fmaxf(v.x, 0.f);
            v.y = fmaxf(v.y, 0.f);
            v.z = fmaxf(v.z, 0.f);
            v.w = fmaxf(v.w, 0.f);
            bf16* Cp = C + (long)bz * cStr + n * M + m;
            bf16x4 ov;
            ov[0] = (bf16)v.x;
            ov[1] = (bf16)v.y;
            ov[2] = (bf16)v.z;
            ov[3] = (bf16)v.w;
            *(bf16x4*)Cp = ov;
        }
    }
}

// ---------------- fused attention block (one block per batch b) --------------
// sv phase reindexed: (f,d) fixed per thread -> D coefficients hoisted to
// registers, halving the LDS-read count of the hottest phase (round-12).
__global__ __launch_bounds__(512) void k_att(
    const bf16* __restrict__ qh, const bf16* __restrict__ keyh,
    const float* __restrict__ src, const float* __restrict__ dct10,
    const float* __restrict__ lw, const float* __restrict__ lb,
    const float* __restrict__ gia, float* __restrict__ dctin,
    bf16* __restrict__ z0) {
    const int b = blockIdx.x;
    const int t = threadIdx.x;
    __shared__ float BIG[9216];
    __shared__ float WD[2400];
    __shared__ float D[350];
    __shared__ float L[1920];
    __shared__ float dinS[960];
    __shared__ float sS[64];
    __shared__ float awS[64];

    {
        const int g = t >> 3, lane = t & 7;
        const int h = g >> 4, tt = g & 15;
        const bf16* q = qh + ((long)h * 256 + b) * 512 + lane * 64;
        const bf16* kr = keyh + (long)h * 2097152 + ((long)b * 16 + tt) * 512 + lane * 64;
        float p = 0.f;
#pragma unroll
        for (int i = 0; i < 8; ++i) {
            const bf16x8 qv = *(const bf16x8*)(q + i * 8);
            const bf16x8 kv = *(const bf16x8*)(kr + i * 8);
#pragma unroll
            for (int j = 0; j < 8; ++j) p = fmaf((float)qv[j], (float)kv[j], p);
        }
        p += __shfl_down(p, 4, 8);
        p += __shfl_down(p, 2, 8);
        p += __shfl_down(p, 1, 8);
        if (lane == 0) sS[g] = p + 1e-15f;
    }
    for (int i = t; i < 2400; i += 512) WD[i] = src[(long)b * 2400 + i];
    for (int i = t; i < 350; i += 512) D[i] = dct10[i];
    __syncthreads();
    if (t < 4) {
        float s = 0.f;
#pragma unroll
        for (int k = 0; k < 16; ++k) s += sS[t * 16 + k];
        const float inv = 1.f / s;
#pragma unroll
        for (int k = 0; k < 16; ++k) awS[t * 16 + k] = sS[t * 16 + k] * inv;
    }
    __syncthreads();
    // sv windows: thread t<480 owns (f=t/10, d=t%10); D row in registers
    if (t < 480) {
        const int f = t / 10, d = t % 10;
        float dreg[35];
#pragma unroll
        for (int v = 0; v < 35; ++v) dreg[v] = D[d * 35 + v];
#pragma unroll 2
        for (int n = 0; n < 16; ++n) {
            float acc = 0.f;
#pragma unroll
            for (int v = 0; v < 35; ++v)
                acc = fmaf(dreg[v], WD[(n + v) * 48 + f], acc);
            BIG[n * 480 + t] = acc;
        }
        // dctin cols 0..9 (gather rows 40..49, last row repeated)
        float acc = 0.f;
#pragma unroll
        for (int v = 0; v < 10; ++v)
            acc = fmaf(dreg[v], WD[(40 + v) * 48 + f], acc);
        float cs = 0.f;
#pragma unroll
        for (int v = 10; v < 35; ++v) cs += dreg[v];
        acc = fmaf(cs, WD[49 * 48 + f], acc);
        dinS[f * 20 + d] = acc;
        dctin[(long)b * 960 + f * 20 + d] = acc;
    }
    __syncthreads();
    for (int p = 0; p < 4; ++p) {
        const int idx = t + p * 512;
        if (idx < 1920) {
            const int h = idx / 480, j = idx % 480;
            float acc = 0.f;
#pragma unroll
            for (int k = 0; k < 16; ++k)
                acc = fmaf(awS[h * 16 + k], BIG[k * 480 + j], acc);
            L[idx] = acc;
        }
    }
    __syncthreads();
    for (int i = t; i < 9216; i += 512) BIG[i] = lw[i];
    for (int i = t; i < 2304; i += 512) WD[i] = gia[i];
    __syncthreads();
    if (t < 480) {
        const int n = t / 10, d = t % 10;
        float acc = lb[n];
#pragma unroll
        for (int h = 0; h < 4; ++h)
#pragma unroll
            for (int f = 0; f < 48; ++f)
                acc = fmaf(BIG[n * 192 + h * 48 + f], L[h * 480 + f * 10 + d], acc);
        dinS[n * 20 + 10 + d] = acc;
        dctin[(long)b * 960 + n * 20 + 10 + d] = acc;
    }
    __syncthreads();
    for (int p = 0; p < 2; ++p) {
        const int idx = t + p * 512;
        if (idx < 960) {
            const int n = idx / 20, d = idx % 20;
            float acc = 0.f;
#pragma unroll
            for (int m = 0; m < 48; ++m)
                acc = fmaf(WD[n * 48 + m], dinS[m * 20 + d], acc);
            z0[((long)b * 48 + n) * 64 + d] = (bf16)acc;
        }
    }
    for (int i = t; i < 2112; i += 512) {
        const int n = i / 44, c = 20 + i % 44;
        z0[((long)b * 48 + n) * 64 + c] = (bf16)0.f;
    }
}

// ---------------- GCN mega-kernel (round-10 version restored) ----------------
__device__ __forceinline__ void gcn_matmul(const bf16* zS, const bf16* Bg,
                                           const int K, const float* bias,
                                           const bf16* resS, bf16* outS,
                                           const int wave, const int lane) {
    const int fr = lane & 15, fq = lane >> 4;
    const int f0 = wave * 32;
    floatx4 acc[3][2];
#pragma unroll
    for (int it = 0; it < 3; ++it)
#pragma unroll
        for (int jt = 0; jt < 2; ++jt) acc[it][jt] = (floatx4){0.f, 0.f, 0.f, 0.f};
    const bf16* bp0 = Bg + (long)(f0 + fr) * K + fq * 8;
    const bf16* bp1 = bp0 + 16 * (long)K;
    bf16x8 bc0 = *(const bf16x8*)(bp0);
    bf16x8 bc1 = *(const bf16x8*)(bp1);
    for (int k0 = 0; k0 < K; k0 += 32) {
        bf16x8 bn0, bn1;
        if (k0 + 32 < K) {
            bn0 = *(const bf16x8*)(bp0 + k0 + 32);
            bn1 = *(const bf16x8*)(bp1 + k0 + 32);
        }
        bf16x8 af[3];
#pragma unroll
        for (int it = 0; it < 3; ++it)
            af[it] = *(const bf16x8*)(zS + (it * 16 + fr) * 520 + k0 + fq * 8);
#pragma unroll
        for (int it = 0; it < 3; ++it) {
            acc[it][0] = __builtin_amdgcn_mfma_f32_16x16x32_bf16(af[it], bc0,
                                                                acc[it][0], 0, 0, 0);
            acc[it][1] = __builtin_amdgcn_mfma_f32_16x16x32_bf16(af[it], bc1,
                                                                acc[it][1], 0, 0, 0);
        }
        bc0 = bn0;
        bc1 = bn1;
    }
#pragma unroll
    for (int jt = 0; jt < 2; ++jt) {
        const int f = f0 + jt * 16 + fr;
        const float bv = bias[f];
#pragma unroll
        for (int it = 0; it < 3; ++it)
#pragma unroll
            for (int r = 0; r < 4; ++r) {
                const int irow = it * 16 + fq * 4 + r;
                float v = tanh_fast((acc[it][jt][r] + bv) * BN_SCALE_F);
                if (resS) v += (float)resS[irow * 520 + f];
                outS[irow * 520 + f] = (bf16)v;
            }
    }
}

__device__ __forceinline__ void gcn_attmul(const bf16* attS, const bf16* yS,
                                           bf16* zS, const int wave,
                                           const int lane) {
    const int fr = lane & 15, fq = lane >> 4;
    const int f0 = wave * 32;
    floatx4 acc[3][2];
#pragma unroll
    for (int it = 0; it < 3; ++it)
#pragma unroll
        for (int jt = 0; jt < 2; ++jt) acc[it][jt] = (floatx4){0.f, 0.f, 0.f, 0.f};
#pragma unroll
    for (int k0 = 0; k0 < 64; k0 += 32) {
        bf16x8 af[3];
#pragma unroll
        for (int it = 0; it < 3; ++it)
            af[it] = *(const bf16x8*)(attS + (it * 16 + fr) * 72 + k0 + fq * 8);
        bf16x8 bfv[2];
#pragma unroll
        for (int jt = 0; jt < 2; ++jt) {
            const int f = f0 + jt * 16 + fr;
            bf16x8 v;
#pragma unroll
            for (int e = 0; e < 8; ++e) {
                int m = k0 + fq * 8 + e;
                m = m < 48 ? m : 47;  // att cols >=48 zero -> clamp safe
                v[e] = yS[m * 520 + f];
            }
            bfv[jt] = v;
        }
#pragma unroll
        for (int it = 0; it < 3; ++it)
#pragma unroll
            for (int jt = 0; jt < 2; ++jt)
                acc[it][jt] = __builtin_amdgcn_mfma_f32_16x16x32_bf16(
                    af[it], bfv[jt], acc[it][jt], 0, 0, 0);
    }
#pragma unroll
    for (int jt = 0; jt < 2; ++jt) {
        const int f = f0 + jt * 16 + fr;
#pragma unroll
        for (int it = 0; it < 3; ++it)
#pragma unroll
            for (int r = 0; r < 4; ++r)
                zS[(it * 16 + fq * 4 + r) * 520 + f] = (bf16)acc[it][jt][r];
    }
}

__global__ __launch_bounds__(1024) void k_gcn(
    const bf16* __restrict__ z0, const bf16* __restrict__ giwP,
    const float* __restrict__ gib, const bf16* __restrict__ gbwt,
    const float* __restrict__ gba, const float* __restrict__ gbb,
    const float* __restrict__ goa, const float* __restrict__ gow,
    const float* __restrict__ gob, const float* __restrict__ dctin,
    const float* __restrict__ dct10, float* __restrict__ out) {
    const int b = blockIdx.x;
    const int t = threadIdx.x;
    const int wave = t >> 6, lane = t & 63;
    __shared__ __align__(16) bf16 yaS[48 * 520];
    __shared__ __align__(16) bf16 ybS[48 * 520];
    __shared__ __align__(16) bf16 zS[48 * 520];
    __shared__ __align__(16) bf16 attS[48 * 72];

    if (t < 384) {
        const int r = t >> 3, c = t & 7;
        *(bf16x8*)(zS + r * 520 + c * 8) =
            *(const bf16x8*)(z0 + ((long)b * 48 + r) * 64 + c * 8);
    }
    __syncthreads();
    gcn_matmul(zS, giwP, 64, gib, nullptr, yaS, wave, lane);
    __syncthreads();

#pragma unroll
    for (int l = 0; l < 4; ++l) {
        bf16* Yin = (l == 0 || l == 3) ? yaS : ybS;
        bf16* Yout = (l < 2) ? ybS : yaS;
        bf16* Res = (l == 1) ? yaS : (l == 3 ? ybS : nullptr);
        for (int i = t; i < 48 * 72; i += 1024) {
            const int rr = i / 72, c = i % 72;
            attS[i] = (bf16)(c < 48 ? gba[l * 2304 + rr * 48 + c] : 0.f);
        }
        __syncthreads();
        gcn_attmul(attS, Yin, zS, wave, lane);
        __syncthreads();
        gcn_matmul(zS, gbwt + (long)l * 262144, 512, gbb + l * 512, Res, Yout,
                   wave, lane);
        __syncthreads();
    }
    // ---- gc_out + iDCT (final Y = yaS) ----
    bf16* GS = zS;                              // [20][520] gow^T
    float* goaS = (float*)((char*)zS + 24576);  // 2304 f32
    float* Df = (float*)attS;                   // 350 f32
    float* T2 = (float*)ybS;                    // 960 f32
    float* dS = ((float*)ybS) + 1024;           // 960 f32
    for (int i = t; i < 10240; i += 1024) {
        const int d = i >> 9, k = i & 511;
        GS[d * 520 + k] = (bf16)gow[k * 20 + d];
    }
    for (int i = t; i < 2304; i += 1024) goaS[i] = goa[i];
    if (t < 350) Df[t] = dct10[t];
    __syncthreads();
    for (int idx = t; idx < 960; idx += 1024) {
        const int m = idx / 20, d = idx % 20;
        float acc = 0.f;
        const bf16* yr = yaS + m * 520;
        const bf16* gr = GS + d * 520;
#pragma unroll 8
        for (int k8 = 0; k8 < 64; ++k8) {
            const bf16x8 yv = *(const bf16x8*)(yr + k8 * 8);
            const bf16x8 gv = *(const bf16x8*)(gr + k8 * 8);
#pragma unroll
            for (int j = 0; j < 8; ++j) acc = fmaf((float)yv[j], (float)gv[j], acc);
        }
        T2[idx] = acc;
    }
    __syncthreads();
    for (int idx = t; idx < 960; idx += 1024) {
        const int n = idx / 20, d = idx % 20;
        float acc = gob[d] + dctin[(long)b * 960 + idx];
#pragma unroll
        for (int m = 0; m < 48; ++m)
            acc = fmaf(goaS[n * 48 + m], T2[m * 20 + d], acc);
        dS[idx] = acc;
    }
    __syncthreads();
    for (int e = t; e < 1680; e += 1024) {
        const int v = e / 48, n = e % 48;
        float acc = 0.f;
#pragma unroll
        for (int d = 0; d < 10; ++d)
            acc = fmaf(Df[d * 35 + v], dS[n * 20 + d], acc);
        out[(long)b * 1680 + e] = acc;
    }
}

// ---------------------------------------------------------------------------
// Workspace (BYTE offsets). keyh bf16 (16.8 MB) aliases WS_T; z0 at WS_T+17MB.
// ---------------------------------------------------------------------------
static constexpr size_t WS_DCT10 = 0;
static constexpr size_t WS_ATTW = 1536;
static constexpr size_t WS_QH = WS_ATTW + 65536;
static constexpr size_t WS_DCTIN = WS_QH + 2097152;
static constexpr size_t WS_DCTOUT = WS_DCTIN + 983040;
static constexpr size_t WS_SRCVAL = WS_DCTOUT + 983040;
static constexpr size_t WS_PAD0 = WS_SRCVAL + 7864320;
static constexpr size_t WS_SRCBF = WS_PAD0 + 8388608;
static constexpr size_t WS_W1TQ = WS_SRCBF + 1229824;
static constexpr size_t WS_W1TK = WS_W1TQ + 1310720;
static constexpr size_t WS_W2TQ = WS_W1TK + 1310720;
static constexpr size_t WS_W2TK = WS_W2TQ + 10485760;
static constexpr size_t WS_GBWT = WS_W2TK + 10485760;
static constexpr size_t WS_R1K = WS_GBWT + 2097152;
static constexpr size_t WS_R1Q = WS_R1K + 20971520;
static constexpr size_t WS_T = WS_R1Q + 5242880;
static constexpr size_t WS_GIWP = WS_T + 50331648;
static constexpr size_t WS_KEYH = WS_T;
static constexpr size_t WS_Z0 = WS_T + 17825792;

extern "C" void kernel_launch(void* const* d_in, const int* in_sizes, int n_in,
                              void* d_out, int out_size, void* d_ws,
                              size_t ws_size, hipStream_t stream) {
    const float* src = (const float*)d_in[0];
    const float* cq1 = (const float*)d_in[1];
    const float* cq2 = (const float*)d_in[2];
    const float* ck1 = (const float*)d_in[3];
    const float* ck2 = (const float*)d_in[4];
    const float* lw = (const float*)d_in[5];
    const float* lb = (const float*)d_in[6];
    const float* giw = (const float*)d_in[7];
    const float* gia = (const float*)d_in[8];
    const float* gib = (const float*)d_in[9];
    const float* gbw = (const float*)d_in[10];
    const float* gba = (const float*)d_in[11];
    const float* gbb = (const float*)d_in[12];
    const float* gow = (const float*)d_in[13];
    const float* goa = (const float*)d_in[14];
    const float* gob = (const float*)d_in[15];
    float* out = (float*)d_out;
    char* ws = (char*)d_ws;

    float* dct10 = (float*)(ws + WS_DCT10);
    bf16* qh = (bf16*)(ws + WS_QH);
    float* dctin = (float*)(ws + WS_DCTIN);
    bf16* keyh = (bf16*)(ws + WS_KEYH);
    bf16* srcbf = (bf16*)(ws + WS_SRCBF);
    bf16* w1tq = (bf16*)(ws + WS_W1TQ);
    bf16* w1tk = (bf16*)(ws + WS_W1TK);
    bf16* w2tq = (bf16*)(ws + WS_W2TQ);
    bf16* w2tk = (bf16*)(ws + WS_W2TK);
    bf16* gbwt = (bf16*)(ws + WS_GBWT);
    bf16* r1k = (bf16*)(ws + WS_R1K);
    bf16* r1q = (bf16*)(ws + WS_R1Q);
    bf16* giwP = (bf16*)(ws + WS_GIWP);
    bf16* z0 = (bf16*)(ws + WS_Z0);

    // 1. all prep in one dispatch (tiled transposes)
    k_prep<<<12003, 256, 0, stream>>>(src, cq1, ck1, cq2, ck2, gbw, giw, dct10,
                                      srcbf, w1tq, w1tk, w2tq, w2tk, gbwt, giwP);

    // 2. conv1 K+Q fused, gridDim.x padded to 56
    {
        GP pk{w1tk, srcbf, r1k, 20, 0, 40, 512L * 320, 0L, 5120L * 512};
        GP pq{w1tq, srcbf, r1q, 5, 40, 10, 512L * 320, 0L, 1280L * 512};
        mgemm2<BM_SRC, BM_SRC><<<dim3(56, 4, 4), 256, 0, stream>>>(pk, pq, 40,
                                                                   512, 320);
    }
    // 3. conv2 K+Q in one 544-block dispatch (K swizzled)
    k_conv2<<<544, 256, 0, stream>>>(w2tk, r1k, keyh, w2tq, r1q, qh);

    // 4. fused attention block -> dctin (fp32), z0 (bf16)
    k_att<<<256, 512, 0, stream>>>(qh, keyh, src, dct10, lw, lb, gia, dctin, z0);

    // 5. whole GCN in one dispatch (round-10 version)
    k_gcn<<<256, 1024, 0, stream>>>(z0, giwP, gib, gbwt, gba, gbb, goa, gow,
                                    gob, dctin, dct10, out);
}